// Round 6
// baseline (287.421 us; speedup 1.0000x reference)
//
#include <hip/hip_runtime.h>
#include <math.h>

#define N_NODES 50000
#define N_EDGES 800000
#define LAGS 16
#define FILT 64
// weight tensor (2, 2, 80, 64): w[d][k][c][f] flat = ((d*2+k)*80 + c)*64 + f
// Only rows c<16 matter (H0 == 0). w_r/b_r entirely dead (R*H0 == 0).
// H = (1-Z)*H_tilde since Z*H0 == 0.
#define W00_OFF 0            // d=0,k=0 identity hop
#define W01_OFF (80*64)      // d=0,k=1 out-diffusion hop
#define W10_OFF (2*80*64)    // d=1,k=0 identity hop
#define W11_OFF (3*80*64)    // d=1,k=1 in-diffusion hop

// HW fp32 fadd atomic. MUST lower to global_atomic_add_f32 (verify in disasm:
// no global_atomic_cmpswap loop). unsafeAtomicAdd does this on gfx90a+
// independent of -munsafe-fp-atomics.
__device__ __forceinline__ void atomAddF(float* p, float v) {
    unsafeAtomicAdd(p, v);
}

// ---------------- kernel 1: weighted degrees ----------------
// 1.6M fp atomics into two N-sized arrays (L2-resident).
__global__ __launch_bounds__(256) void deg_kernel(
    const int* __restrict__ row, const int* __restrict__ col,
    const float* __restrict__ ew,
    float* __restrict__ deg_out, float* __restrict__ deg_in)
{
    for (int e = blockIdx.x * 256 + threadIdx.x; e < N_EDGES;
         e += gridDim.x * 256) {
        float w = ew[e];
        atomAddF(&deg_out[row[e]], w);
        atomAddF(&deg_in[col[e]], w);
    }
}

// ---------------- kernel 2: guarded reciprocal + pre-scaled features -------
// Xs_o[n] = x[n] * (deg_out[n] > 0 ? 1/deg_out[n] : 1)
// Xs_i[n] = x[n] * (deg_in[n]  > 0 ? 1/deg_in[n]  : 1)
// Folding the source-side norm here removes all per-edge norm loads.
__global__ __launch_bounds__(256) void scale_kernel(
    const float* __restrict__ x,
    const float* __restrict__ deg_out, const float* __restrict__ deg_in,
    float* __restrict__ Xs_o, float* __restrict__ Xs_i)
{
    for (int n = blockIdx.x * 256 + threadIdx.x; n < N_NODES;
         n += gridDim.x * 256) {
        float d_o = deg_out[n];
        float d_i = deg_in[n];
        float io = (d_o > 0.0f) ? (1.0f / d_o) : 1.0f;
        float ii = (d_i > 0.0f) ? (1.0f / d_i) : 1.0f;
        const float4* px = (const float4*)(x + (size_t)n * LAGS);
        float4* po = (float4*)(Xs_o + (size_t)n * LAGS);
        float4* pi = (float4*)(Xs_i + (size_t)n * LAGS);
#pragma unroll
        for (int q = 0; q < 4; ++q) {
            float4 v = px[q];
            po[q] = make_float4(io * v.x, io * v.y, io * v.z, io * v.w);
            pi[q] = make_float4(ii * v.x, ii * v.y, ii * v.z, ii * v.w);
        }
    }
}

// ---------------- kernel 3: edge scatter, lane-per-channel ----------------
// 16 lanes own one edge (lane ch = tid&15 handles channel ch):
//   Tx_o[col][ch] += Xs_o[row][ch];  Tx_i[row][ch] += Xs_i[col][ch]
// Wave-level: feature loads are coalesced 64B rows (4 lines/instr instead of
// 64 for thread-per-edge), atomics packed ~8 lines/instr. Index loads are
// same-address across each 16-lane group (HW-merged). Atomic lane-op count
// is the invariant of the scatter approach: 25.6M. Grid capped at 2048
// blocks (G11); each thread runs ~25 independent lane-tasks (loop ILP).
__global__ __launch_bounds__(256) void scatter_kernel(
    const int* __restrict__ row, const int* __restrict__ col,
    const float* __restrict__ Xs_o, const float* __restrict__ Xs_i,
    float* __restrict__ Tx_o, float* __restrict__ Tx_i)
{
    const int total = N_EDGES * 16;   // 12.8M lane-tasks, fits int32
    for (int t = blockIdx.x * 256 + threadIdx.x; t < total;
         t += gridDim.x * 256) {
        int e  = t >> 4;
        int ch = t & 15;
        int r = row[e], c = col[e];
        float vo = Xs_o[(size_t)r * LAGS + ch];
        float vi = Xs_i[(size_t)c * LAGS + ch];
        atomAddF(&Tx_o[(size_t)c * LAGS + ch], vo);
        atomAddF(&Tx_i[(size_t)r * LAGS + ch], vi);
    }
}

// ---------------- kernel 4: fused per-node gates + head ----------------
// gz = x@(Wz00+Wz10)[:16] + Tx_o@Wz01[:16] + Tx_i@Wz11[:16] + bz
// gh = same with w_h
// out = relu((1-sigmoid(gz))*tanh(gh)) @ lin_w + lin_b
// Weights staged transposed in LDS (float4 broadcast reads). 1 node/thread:
// 196 blocks -> 77% CU coverage (2 nodes/thread gave only 98 blocks = 38%).
// az/ah give dependent-FMA spacing 2 issue-slots = 4 cyc = FMA latency, and
// filter iterations are independent -> issue-bound.
__global__ __launch_bounds__(256) void node_kernel(
    const float* __restrict__ x,
    const float* __restrict__ Tx_o, const float* __restrict__ Tx_i,
    const float* __restrict__ w_z, const float* __restrict__ b_z,
    const float* __restrict__ w_h, const float* __restrict__ b_h,
    const float* __restrict__ lin_w, const float* __restrict__ lin_b,
    float* __restrict__ out)
{
    __shared__ float Wzc[FILT * 16], Wzo[FILT * 16], Wzi[FILT * 16];
    __shared__ float Whc[FILT * 16], Who[FILT * 16], Whi[FILT * 16];
    __shared__ float sbz[FILT], sbh[FILT], slw[FILT];

    const int tid = threadIdx.x;
    for (int i = tid; i < FILT * 16; i += 256) {
        int c = i >> 6, f = i & 63;           // global reads coalesced over f
        int t = f * 16 + c;
        int g = c * 64 + f;
        Wzc[t] = w_z[W00_OFF + g] + w_z[W10_OFF + g];
        Wzo[t] = w_z[W01_OFF + g];
        Wzi[t] = w_z[W11_OFF + g];
        Whc[t] = w_h[W00_OFF + g] + w_h[W10_OFF + g];
        Who[t] = w_h[W01_OFF + g];
        Whi[t] = w_h[W11_OFF + g];
    }
    if (tid < FILT) {
        sbz[tid] = b_z[tid];
        sbh[tid] = b_h[tid];
        slw[tid] = lin_w[tid];
    }
    __syncthreads();

    int n = blockIdx.x * 256 + tid;
    if (n >= N_NODES) return;

    float v[48];   // x | Tx_o | Tx_i, 16 each
    {
        float4* vv = (float4*)v;
        const float4* px = (const float4*)(x    + (size_t)n * LAGS);
        const float4* po = (const float4*)(Tx_o + (size_t)n * LAGS);
        const float4* pi = (const float4*)(Tx_i + (size_t)n * LAGS);
#pragma unroll
        for (int q = 0; q < 4; ++q) {
            vv[q] = px[q]; vv[4 + q] = po[q]; vv[8 + q] = pi[q];
        }
    }

    float acc = 0.0f;
    for (int f = 0; f < FILT; ++f) {
        float az = sbz[f], ah = sbh[f];
        const float4* wzc = (const float4*)&Wzc[f * 16];
        const float4* wzo = (const float4*)&Wzo[f * 16];
        const float4* wzi = (const float4*)&Wzi[f * 16];
        const float4* whc = (const float4*)&Whc[f * 16];
        const float4* who = (const float4*)&Who[f * 16];
        const float4* whi = (const float4*)&Whi[f * 16];
#pragma unroll
        for (int q = 0; q < 4; ++q) {
            float4 a = wzc[q], b = wzo[q], cc = wzi[q];
            float4 d = whc[q], e = who[q], g = whi[q];
            const float* vx = &v[q * 4];
            const float* vo = &v[16 + q * 4];
            const float* vi = &v[32 + q * 4];
            az = fmaf(vx[0], a.x, az);  ah = fmaf(vx[0], d.x, ah);
            az = fmaf(vx[1], a.y, az);  ah = fmaf(vx[1], d.y, ah);
            az = fmaf(vx[2], a.z, az);  ah = fmaf(vx[2], d.z, ah);
            az = fmaf(vx[3], a.w, az);  ah = fmaf(vx[3], d.w, ah);
            az = fmaf(vo[0], b.x, az);  ah = fmaf(vo[0], e.x, ah);
            az = fmaf(vo[1], b.y, az);  ah = fmaf(vo[1], e.y, ah);
            az = fmaf(vo[2], b.z, az);  ah = fmaf(vo[2], e.z, ah);
            az = fmaf(vo[3], b.w, az);  ah = fmaf(vo[3], e.w, ah);
            az = fmaf(vi[0], cc.x, az); ah = fmaf(vi[0], g.x, ah);
            az = fmaf(vi[1], cc.y, az); ah = fmaf(vi[1], g.y, ah);
            az = fmaf(vi[2], cc.z, az); ah = fmaf(vi[2], g.z, ah);
            az = fmaf(vi[3], cc.w, az); ah = fmaf(vi[3], g.w, ah);
        }
        float z = 1.0f / (1.0f + __expf(-az));                 // sigmoid
        float th = 1.0f - 2.0f / (__expf(2.0f * ah) + 1.0f);   // tanh
        acc = fmaf(fmaxf((1.0f - z) * th, 0.0f), slw[f], acc);
    }
    out[n] = acc + lin_b[0];
}

extern "C" void kernel_launch(void* const* d_in, const int* in_sizes, int n_in,
                              void* d_out, int out_size, void* d_ws, size_t ws_size,
                              hipStream_t stream)
{
    const float* x      = (const float*)d_in[0];
    const int*   eidx   = (const int*)d_in[1];      // (2, E) int32 per harness
    const float* ew     = (const float*)d_in[2];
    const float* w_z    = (const float*)d_in[3];
    const float* b_z    = (const float*)d_in[4];
    // d_in[5], d_in[6] = w_r, b_r : dead (H0 == 0 => R*H0 == 0)
    const float* w_h    = (const float*)d_in[7];
    const float* b_h    = (const float*)d_in[8];
    const float* lin_w  = (const float*)d_in[9];
    const float* lin_b  = (const float*)d_in[10];
    float* out = (float*)d_out;

    const int* row = eidx;            // edge_index[0]
    const int* col = eidx + N_EDGES;  // edge_index[1]

    // workspace layout (floats); first (2+32)N zeroed each call (harness
    // re-poisons ws to 0xAA before every timed launch). Total 66N = 13.2 MB.
    float* ws      = (float*)d_ws;
    float* deg_out = ws;                                 // N
    float* deg_in  = ws + N_NODES;                       // N
    float* Tx_o    = ws + 2 * N_NODES;                   // 16N
    float* Tx_i    = ws + 2 * N_NODES + 16 * N_NODES;    // 16N
    float* Xs_o    = ws + 2 * N_NODES + 32 * N_NODES;    // 16N (fully written)
    float* Xs_i    = ws + 2 * N_NODES + 48 * N_NODES;    // 16N (fully written)

    hipMemsetAsync(d_ws, 0, (size_t)(2 + 32) * N_NODES * sizeof(float), stream);

    int eb = 2048;                    // grid-stride, G11 cap
    deg_kernel<<<eb, 256, 0, stream>>>(row, col, ew, deg_out, deg_in);

    int nb = (N_NODES + 255) / 256;
    scale_kernel<<<nb, 256, 0, stream>>>(x, deg_out, deg_in, Xs_o, Xs_i);

    int sb = 2048;                    // grid-stride over 12.8M lane-tasks
    scatter_kernel<<<sb, 256, 0, stream>>>(row, col, Xs_o, Xs_i, Tx_o, Tx_i);

    node_kernel<<<nb, 256, 0, stream>>>(x, Tx_o, Tx_i, w_z, b_z, w_h, b_h,
                                        lin_w, lin_b, out);
}